// Round 7
// baseline (311.862 us; speedup 1.0000x reference)
//
#include <hip/hip_runtime.h>
#include <cstdint>
#include <cstddef>

// Problem constants (fixed by setup_inputs)
#define ZSEQ 8
#define NSEQ 2048
#define NH 4
#define DH 128
#define QKV_STRIDE (NH * 3 * DH) /* 1536 floats per token row */
#define OUT_STRIDE (NH * DH)     /* 512 floats per token row */
#define ALPHA 0.08838834764831843f
#define TILE_B 16384             /* bytes per 64-row K tile / per V tile */

typedef _Float16 h8 __attribute__((ext_vector_type(8)));
typedef __fp16 fp16x2 __attribute__((ext_vector_type(2)));
typedef float fx16 __attribute__((ext_vector_type(16)));
typedef unsigned int ui4v __attribute__((ext_vector_type(4)));
typedef unsigned short u16t;

// global_load_lds: per-lane global src, wave-uniform LDS base (HW adds lane*16)
#define GLDS(gp, lp)                                                        \
  __builtin_amdgcn_global_load_lds(                                         \
      (__attribute__((address_space(1))) void*)(gp),                        \
      (__attribute__((address_space(3))) void*)(lp), 16, 0, 0)

__device__ __forceinline__ h8 cvt8(float4 a, float4 b) {
  h8 r;
  r[0] = (_Float16)a.x; r[1] = (_Float16)a.y; r[2] = (_Float16)a.z; r[3] = (_Float16)a.w;
  r[4] = (_Float16)b.x; r[5] = (_Float16)b.y; r[6] = (_Float16)b.z; r[7] = (_Float16)b.w;
  return r;
}

__device__ __forceinline__ unsigned pku(float a, float b) {
  union { fp16x2 h; unsigned u; } c;
  c.h = __builtin_amdgcn_cvt_pkrtz(a, b);
  return c.u;
}

// ---------------------------------------------------------------------------
// Prep: qkv f32 -> pre-swizzled f16 tiles in d_ws.
//   K tiles: [zh][nt][64 rows x 256B], byte col c stored at c ^ ((row&7)<<4)
//   V tiles: [zh][nt][128 d-rows x 128B], col c stored at c ^ ((d&7)<<4)
//   V tile COLUMN ORDER is bit2<->bit3 swapped in n (pi(c) = swap bits 2,3):
//   column c holds V row n0 + pi(c). This matches the natural per-lane order
//   of S^T fragments after swapped-QK^T MFMA, so PV needs NO cross-lane ops.
// ---------------------------------------------------------------------------
__global__ __launch_bounds__(256) void prep_kernel(const float* __restrict__ qkv,
                                                   const int* __restrict__ seq_offsets,
                                                   char* __restrict__ k16,
                                                   char* __restrict__ vt) {
  __shared__ u16t Vl[64 * 136];  // padded transpose staging
  const int t = threadIdx.x;
  const int b = blockIdx.x;
  const int z = b >> 7;
  const int h = (b >> 5) & 3;
  const int nb = b & 31;
  const int n0 = nb * 64;
  const int start = seq_offsets[z];
  const int zh = z * NH + h;
  const size_t tb = (size_t)(zh * 32 + nb) * TILE_B;

#pragma unroll
  for (int i = 0; i < 2; ++i) {
    const int r = i * 32 + (t >> 3);
    const int c16 = (t & 7) * 16;  // element col
    const int cb = c16 * 2;        // byte col
    const float* src = qkv + (size_t)(start + n0 + r) * QKV_STRIDE + h * (3 * DH);
    // ---- K (swizzled) ----
    float4 a0 = *(const float4*)(src + DH + c16);
    float4 a1 = *(const float4*)(src + DH + c16 + 4);
    float4 a2 = *(const float4*)(src + DH + c16 + 8);
    float4 a3 = *(const float4*)(src + DH + c16 + 12);
    char* kd = k16 + tb + r * 256;
    *(h8*)(kd + (cb ^ ((r & 7) << 4))) = cvt8(a0, a1);
    *(h8*)(kd + ((cb + 16) ^ ((r & 7) << 4))) = cvt8(a2, a3);
    // ---- V -> LDS (row-major, padded) ----
    float4 v0 = *(const float4*)(src + 2 * DH + c16);
    float4 v1 = *(const float4*)(src + 2 * DH + c16 + 4);
    float4 v2 = *(const float4*)(src + 2 * DH + c16 + 8);
    float4 v3 = *(const float4*)(src + 2 * DH + c16 + 12);
    *(h8*)((char*)Vl + r * 272 + cb) = cvt8(v0, v1);
    *(h8*)((char*)Vl + r * 272 + cb + 16) = cvt8(v2, v3);
  }
  __syncthreads();
  // transpose out: V tile rows = d, cols = n with pi (bits 2,3 of n swapped)
#pragma unroll
  for (int j = 0; j < 2; ++j) {
    const int d = j * 64 + (t >> 2);
    const int n16 = (t & 3) * 16;
    const int cn = n16 * 2;  // byte col of this 16-col group
    h8 o0, o1;
    // column group c = 0..7 holds rows {0,1,2,3, 8,9,10,11} + n16
    // column group c = 8..15 holds rows {4,5,6,7, 12,13,14,15} + n16
#pragma unroll
    for (int k2 = 0; k2 < 8; ++k2) {
      const int r0 = (k2 & 3) + 8 * (k2 >> 2);
      o0[k2] = *(const _Float16*)((const char*)Vl + (n16 + r0) * 272 + d * 2);
      o1[k2] = *(const _Float16*)((const char*)Vl + (n16 + 4 + r0) * 272 + d * 2);
    }
    char* vd = vt + tb + d * 128;
    *(h8*)(vd + (cn ^ ((d & 7) << 4))) = o0;
    *(h8*)(vd + ((cn + 16) ^ ((d & 7) << 4))) = o1;
  }
}

// silu + causal mask on one S^T accumulator (in place).
// s element i holds S^T at n = n0 + nbase + (i&3) + 8*(i>>2) + 4*lh, col m=mrow.
__device__ __forceinline__ void silu_mask(fx16& s, int nbase, bool needmask, int n0,
                                          int mrow, int lh) {
#pragma unroll
  for (int i = 0; i < 16; ++i) {
    const float sv = s[i];
    float sil = sv * __builtin_amdgcn_rcpf((1.0f + __expf(-sv)) * 2048.0f);
    if (needmask && (n0 + nbase + (i & 3) + 8 * (i >> 2) + 4 * lh > mrow)) sil = 0.0f;
    s[i] = sil;
  }
}

// pack 8 consecutive s elements (b = 0 or 8) into an f16 A-fragment.
// Fragment element j (= k-offset) gets s[b+j]; combined with the pi-permuted
// V column order this makes PV exact. No cross-lane ops.
__device__ __forceinline__ h8 pack8(const fx16& s, int b) {
  union { ui4v u; h8 h; } cv;
  cv.u = (ui4v){pku(s[b + 0], s[b + 1]), pku(s[b + 2], s[b + 3]),
                pku(s[b + 4], s[b + 5]), pku(s[b + 6], s[b + 7])};
  return cv.h;
}

// ---------------------------------------------------------------------------
// Attention r7: BM=64, 2-wave (128-thread) blocks, 1024 blocks = 32 zh x 32
// m-tiles, heavy-first (mt = 31 - (bid>>5)). KV tile 64, SINGLE 32KB LDS
// buffer (5 blocks/CU by LDS; grid gives ~4/CU => ~8 waves/CU co-resident,
// ~2x r6's effective occupancy). Every wave computes every kt <= mt; exactly
// one masked diagonal tile per wave. Inter-block TLP hides staging + LDS
// latency (no intra-block prefetch needed). Inner loop layout identical to
// the verified r4/r6 kernel.
// ---------------------------------------------------------------------------
__global__ __launch_bounds__(128, 3) void attn_kernel(const float* __restrict__ qkv,
                                                      const int* __restrict__ seq_offsets,
                                                      const char* __restrict__ k16,
                                                      const char* __restrict__ vt,
                                                      float* __restrict__ out) {
  __shared__ u16t Ks[64 * 128];   // 16KB
  __shared__ u16t Vs[128 * 64];   // 16KB

  const int t = threadIdx.x;
  const int lane = t & 63;
  const int w = t >> 6;          // 0/1
  const int l31 = lane & 31;
  const int lh = lane >> 5;

  const int bid = blockIdx.x;
  const int zh = bid & 31;       // all blocks of a zh land on the same XCD (%8)
  const int mt = 31 - (bid >> 5);  // heavy-first dispatch
  const int z = zh >> 2;
  const int h = zh & 3;

  const int start = seq_offsets[z];
  const int wm0 = mt * 64 + w * 32;  // seq-local first row of this wave
  const int mrow = wm0 + l31;        // this lane's output row (seq-local)

  // ---- Q fragments (B-operand: col=m=l31, k=d), pre-scaled by ALPHA ----
  h8 qf[8];
  {
    const float* qrow = qkv + (size_t)(start + mrow) * QKV_STRIDE + h * (3 * DH);
#pragma unroll
    for (int ks = 0; ks < 8; ++ks) {
      const int d0 = ks * 16 + lh * 8;
      float4 a = *(const float4*)(qrow + d0);
      float4 b = *(const float4*)(qrow + d0 + 4);
      a.x *= ALPHA; a.y *= ALPHA; a.z *= ALPHA; a.w *= ALPHA;
      b.x *= ALPHA; b.y *= ALPHA; b.z *= ALPHA; b.w *= ALPHA;
      qf[ks] = cvt8(a, b);
    }
  }

  fx16 oacc[4];
#pragma unroll
  for (int db = 0; db < 4; ++db)
#pragma unroll
    for (int i = 0; i < 16; ++i) oacc[db][i] = 0.0f;

  const size_t tbase = (size_t)(zh * 32) * TILE_B;

  // stage tile kt2 into the single buffer (16 global_load_lds per thread pair
  // of waves; each wave covers interleaved 1KB chunks)
  auto stage = [&](int kt2) {
    const char* kg = k16 + tbase + (size_t)kt2 * TILE_B + w * 1024 + lane * 16;
    const char* vg = vt + tbase + (size_t)kt2 * TILE_B + w * 1024 + lane * 16;
    u16t* kl = &Ks[w * 512];   // u16 units: 512 u16 = 1KB
    u16t* vl = &Vs[w * 512];
#pragma unroll
    for (int i = 0; i < 8; ++i) {
      GLDS(kg + i * 2048, kl + i * 1024);
      GLDS(vg + i * 2048, vl + i * 1024);
    }
  };

  for (int kt = 0; kt <= mt; ++kt) {
    stage(kt);
    __syncthreads();  // staging landed (vmcnt drained per-wave at barrier)

    const int n0 = kt * 64;
    const char* kb = (const char*)&Ks[0];
    const char* vb = (const char*)&Vs[0];

    // ---- batch ALL 16 K-fragment reads (independent -> pipelined) ----
    h8 a0[8], a1[8];
    const int sw = (l31 & 7) << 4;
#pragma unroll
    for (int ks = 0; ks < 8; ++ks) {
      const int cb = 32 * ks + 16 * lh;
      a0[ks] = *(const h8*)(kb + l31 * 256 + (cb ^ sw));
      a1[ks] = *(const h8*)(kb + (32 + l31) * 256 + (cb ^ sw));
    }
    // ---- S^T = K Q^T (A=K rows n, B=Q cols m) ----
    fx16 s0, s1;
#pragma unroll
    for (int i = 0; i < 16; ++i) { s0[i] = 0.0f; s1[i] = 0.0f; }
    __builtin_amdgcn_s_setprio(1);
#pragma unroll
    for (int ks = 0; ks < 8; ++ks) {
      s0 = __builtin_amdgcn_mfma_f32_32x32x16_f16(a0[ks], qf[ks], s0, 0, 0, 0);
      s1 = __builtin_amdgcn_mfma_f32_32x32x16_f16(a1[ks], qf[ks], s1, 0, 0, 0);
    }
    __builtin_amdgcn_s_setprio(0);

    // ---- batch ALL 16 V-fragment reads; silu VALU hides their latency ----
    h8 bv[4][4];
#pragma unroll
    for (int ks = 0; ks < 4; ++ks) {
      const int cb = 32 * ks + 16 * lh;
#pragma unroll
      for (int db = 0; db < 4; ++db) {
        const int rr = db * 32 + l31;
        bv[ks][db] = *(const h8*)(vb + rr * 128 + (cb ^ ((rr & 7) << 4)));
      }
    }
    // ---- silu + mask (in-register), pack to PV A-fragments ----
    const bool needmask = (kt == mt);
    silu_mask(s0, 0, needmask, n0, mrow, lh);
    silu_mask(s1, 32, needmask, n0, mrow, lh);
    h8 pa[4];
    pa[0] = pack8(s0, 0);
    pa[1] = pack8(s0, 8);
    pa[2] = pack8(s1, 0);
    pa[3] = pack8(s1, 8);
    // ---- O += P V ----  (V columns are pi-permuted to match pa order)
    __builtin_amdgcn_s_setprio(1);
#pragma unroll
    for (int ks = 0; ks < 4; ++ks) {
#pragma unroll
      for (int db = 0; db < 4; ++db) {
        oacc[db] = __builtin_amdgcn_mfma_f32_32x32x16_f16(pa[ks], bv[ks][db], oacc[db], 0, 0, 0);
      }
    }
    __builtin_amdgcn_s_setprio(0);

    __syncthreads();  // gate buffer reuse by next stage
  }

  // ---- epilogue: f32 output ----
#pragma unroll
  for (int db = 0; db < 4; ++db) {
    const int d = db * 32 + l31;
#pragma unroll
    for (int i = 0; i < 16; ++i) {
      const int m = wm0 + (i & 3) + 8 * (i >> 2) + 4 * lh;
      out[(size_t)(start + m) * OUT_STRIDE + h * DH + d] = oacc[db][i];
    }
  }
}

// ---------------------------------------------------------------------------
// Never-expected fallback (ws too small): naive per-(token,head) block.
// ---------------------------------------------------------------------------
__global__ __launch_bounds__(128) void fallback_kernel(const float* __restrict__ qkv,
                                                       const int* __restrict__ seq_offsets,
                                                       float* __restrict__ out) {
  const int token = blockIdx.x;
  const int h = blockIdx.y;
  const int z = token >> 11;
  const int m = token & 2047;
  const int start = seq_offsets[z];
  const int t = threadIdx.x;  // = d
  const float qd = qkv[(size_t)(start + m) * QKV_STRIDE + h * (3 * DH) + t] * ALPHA;
  __shared__ float red[2];
  float acc = 0.0f;
  for (int n = 0; n <= m; ++n) {
    const float kd = qkv[(size_t)(start + n) * QKV_STRIDE + h * (3 * DH) + DH + t];
    float part = qd * kd;
#pragma unroll
    for (int o = 32; o; o >>= 1) part += __shfl_down(part, o);
    if ((t & 63) == 0) red[t >> 6] = part;
    __syncthreads();
    const float s = red[0] + red[1];
    const float sil = s / ((1.0f + __expf(-s)) * 2048.0f);
    acc += sil * qkv[(size_t)(start + n) * QKV_STRIDE + h * (3 * DH) + 2 * DH + t];
    __syncthreads();
  }
  out[(size_t)(start + m) * OUT_STRIDE + h * DH + t] = acc;
}

// ---------------------------------------------------------------------------
extern "C" void kernel_launch(void* const* d_in, const int* in_sizes, int n_in,
                              void* d_out, int out_size, void* d_ws, size_t ws_size,
                              hipStream_t stream) {
  (void)in_sizes; (void)n_in; (void)out_size;
  const float* qkv = (const float*)d_in[0];
  const int* seq_offsets = (const int*)d_in[1];
  // d_in[2..4] (timestamps, ts_weights, pos_weights) unused by the reference.
  float* out = (float*)d_out;

  const size_t half = (size_t)ZSEQ * NH * 32 * TILE_B;  // 16 MiB (bytes)

  if (ws_size >= 2 * half) {
    char* k16 = (char*)d_ws;
    char* vt = k16 + half;
    prep_kernel<<<ZSEQ * NH * (NSEQ / 64), 256, 0, stream>>>(qkv, seq_offsets, k16, vt);
    attn_kernel<<<ZSEQ * NH * 32, 128, 0, stream>>>(qkv, seq_offsets, k16, vt, out);
  } else {
    fallback_kernel<<<dim3(ZSEQ * NSEQ, NH), 128, 0, stream>>>(qkv, seq_offsets, out);
  }
}

// Round 8
// 97.243 us; speedup vs baseline: 3.2071x; 3.2071x over previous
//
#include <hip/hip_runtime.h>
#include <cstdint>
#include <cstddef>

// Problem constants (fixed by setup_inputs)
#define ZSEQ 8
#define NSEQ 2048
#define NH 4
#define DH 128
#define QKV_STRIDE (NH * 3 * DH) /* 1536 floats per token row */
#define OUT_STRIDE (NH * DH)     /* 512 floats per token row */
#define ALPHA 0.08838834764831843f
#define LOG2E 1.4426950408889634f
#define QSCALE (ALPHA * LOG2E)                 /* fold log2e into Q */
#define VSCALE (1.0f / (2048.0f * LOG2E))      /* fold 1/(2048*log2e) into V */
#define TILE_B 16384             /* bytes per 64-row K tile / per V tile */

typedef _Float16 h8 __attribute__((ext_vector_type(8)));
typedef __fp16 fp16x2 __attribute__((ext_vector_type(2)));
typedef float fx16 __attribute__((ext_vector_type(16)));
typedef unsigned int ui4v __attribute__((ext_vector_type(4)));
typedef unsigned short u16t;

// global_load_lds: per-lane global src, wave-uniform LDS base (HW adds lane*16)
#define GLDS(gp, lp)                                                        \
  __builtin_amdgcn_global_load_lds(                                         \
      (__attribute__((address_space(1))) void*)(gp),                        \
      (__attribute__((address_space(3))) void*)(lp), 16, 0, 0)

__device__ __forceinline__ h8 cvt8(float4 a, float4 b) {
  h8 r;
  r[0] = (_Float16)a.x; r[1] = (_Float16)a.y; r[2] = (_Float16)a.z; r[3] = (_Float16)a.w;
  r[4] = (_Float16)b.x; r[5] = (_Float16)b.y; r[6] = (_Float16)b.z; r[7] = (_Float16)b.w;
  return r;
}

__device__ __forceinline__ unsigned pku(float a, float b) {
  union { fp16x2 h; unsigned u; } c;
  c.h = __builtin_amdgcn_cvt_pkrtz(a, b);
  return c.u;
}

// ---------------------------------------------------------------------------
// Prep: qkv f32 -> pre-swizzled f16 tiles in d_ws.
//   K tiles: [zh][nt][64 rows x 256B], byte col c stored at c ^ ((row&7)<<4)
//   V tiles: [zh][nt][128 d-rows x 128B], col c stored at c ^ ((d&7)<<4)
//   V values pre-scaled by VSCALE (silu exp2/2048 folding).
//   V tile COLUMN ORDER is bit2<->bit3 swapped in n (pi(c) = swap bits 2,3):
//   column c holds V row n0 + pi(c). This matches the natural per-lane order
//   of S^T fragments after swapped-QK^T MFMA, so PV needs NO cross-lane ops.
// ---------------------------------------------------------------------------
__global__ __launch_bounds__(256) void prep_kernel(const float* __restrict__ qkv,
                                                   const int* __restrict__ seq_offsets,
                                                   char* __restrict__ k16,
                                                   char* __restrict__ vt) {
  __shared__ u16t Vl[64 * 136];  // padded transpose staging
  const int t = threadIdx.x;
  const int b = blockIdx.x;
  const int z = b >> 7;
  const int h = (b >> 5) & 3;
  const int nb = b & 31;
  const int n0 = nb * 64;
  const int start = seq_offsets[z];
  const int zh = z * NH + h;
  const size_t tb = (size_t)(zh * 32 + nb) * TILE_B;

#pragma unroll
  for (int i = 0; i < 2; ++i) {
    const int r = i * 32 + (t >> 3);
    const int c16 = (t & 7) * 16;  // element col
    const int cb = c16 * 2;        // byte col
    const float* src = qkv + (size_t)(start + n0 + r) * QKV_STRIDE + h * (3 * DH);
    // ---- K (swizzled) ----
    float4 a0 = *(const float4*)(src + DH + c16);
    float4 a1 = *(const float4*)(src + DH + c16 + 4);
    float4 a2 = *(const float4*)(src + DH + c16 + 8);
    float4 a3 = *(const float4*)(src + DH + c16 + 12);
    char* kd = k16 + tb + r * 256;
    *(h8*)(kd + (cb ^ ((r & 7) << 4))) = cvt8(a0, a1);
    *(h8*)(kd + ((cb + 16) ^ ((r & 7) << 4))) = cvt8(a2, a3);
    // ---- V -> LDS (row-major, padded), pre-scaled by VSCALE ----
    float4 v0 = *(const float4*)(src + 2 * DH + c16);
    float4 v1 = *(const float4*)(src + 2 * DH + c16 + 4);
    float4 v2 = *(const float4*)(src + 2 * DH + c16 + 8);
    float4 v3 = *(const float4*)(src + 2 * DH + c16 + 12);
    v0.x *= VSCALE; v0.y *= VSCALE; v0.z *= VSCALE; v0.w *= VSCALE;
    v1.x *= VSCALE; v1.y *= VSCALE; v1.z *= VSCALE; v1.w *= VSCALE;
    v2.x *= VSCALE; v2.y *= VSCALE; v2.z *= VSCALE; v2.w *= VSCALE;
    v3.x *= VSCALE; v3.y *= VSCALE; v3.z *= VSCALE; v3.w *= VSCALE;
    *(h8*)((char*)Vl + r * 272 + cb) = cvt8(v0, v1);
    *(h8*)((char*)Vl + r * 272 + cb + 16) = cvt8(v2, v3);
  }
  __syncthreads();
  // transpose out: V tile rows = d, cols = n with pi (bits 2,3 of n swapped)
#pragma unroll
  for (int j = 0; j < 2; ++j) {
    const int d = j * 64 + (t >> 2);
    const int n16 = (t & 3) * 16;
    const int cn = n16 * 2;  // byte col of this 16-col group
    h8 o0, o1;
#pragma unroll
    for (int k2 = 0; k2 < 8; ++k2) {
      const int r0 = (k2 & 3) + 8 * (k2 >> 2);
      o0[k2] = *(const _Float16*)((const char*)Vl + (n16 + r0) * 272 + d * 2);
      o1[k2] = *(const _Float16*)((const char*)Vl + (n16 + 4 + r0) * 272 + d * 2);
    }
    char* vd = vt + tb + d * 128;
    *(h8*)(vd + (cn ^ ((d & 7) << 4))) = o0;
    *(h8*)(vd + ((cn + 16) ^ ((d & 7) << 4))) = o1;
  }
}

// silu + causal mask on one S^T accumulator (in place).
// s holds s2 = (alpha*log2e) * q.k; silu_ref/2048 = VSCALE * s2*rcp(1+2^-s2),
// with VSCALE folded into V. s element i at n = n0+nbase+(i&3)+8*(i>>2)+4*lh.
__device__ __forceinline__ void silu_mask(fx16& s, int nbase, bool needmask, int n0,
                                          int mrow, int lh) {
#pragma unroll
  for (int i = 0; i < 16; ++i) {
    const float sv = s[i];
    const float e2 = __builtin_amdgcn_exp2f(-sv);
    float sil = sv * __builtin_amdgcn_rcpf(1.0f + e2);
    if (needmask && (n0 + nbase + (i & 3) + 8 * (i >> 2) + 4 * lh > mrow)) sil = 0.0f;
    s[i] = sil;
  }
}

// pack 8 consecutive s elements (b = 0 or 8) into an f16 A-fragment.
__device__ __forceinline__ h8 pack8(const fx16& s, int b) {
  union { ui4v u; h8 h; } cv;
  cv.u = (ui4v){pku(s[b + 0], s[b + 1]), pku(s[b + 2], s[b + 3]),
                pku(s[b + 4], s[b + 5]), pku(s[b + 6], s[b + 7])};
  return cv.h;
}

// ---------------------------------------------------------------------------
// Attention r8 "sequential fold": 256 blocks = 32 zh x 8 folds, 4 waves,
// BM=128, KV tile 64, double-buffered LDS (64KB) + 20KB dynamic reserve to
// force 1 block/CU. Block f computes m-tile f (kv span 2f+2 tiles) THEN
// m-tile 15-f (span 32-2f): total 34 staged tiles for EVERY block ->
// perfectly uniform CU durations, r4-level staging traffic, no tail.
// Inner loop identical to verified r4/r6 (swapped QK^T, in-reg silu,
// pi-permuted V, batched LDS reads, setprio).
// ---------------------------------------------------------------------------
__global__ __launch_bounds__(256, 1) void attn_kernel(const float* __restrict__ qkv,
                                                      const int* __restrict__ seq_offsets,
                                                      const char* __restrict__ k16,
                                                      const char* __restrict__ vt,
                                                      float* __restrict__ out) {
  __shared__ u16t Ks[2][64 * 128];   // 16KB per buf
  __shared__ u16t Vs[2][128 * 64];   // 16KB per buf

  const int t = threadIdx.x;
  const int lane = t & 63;
  const int w = t >> 6;
  const int l31 = lane & 31;
  const int lh = lane >> 5;

  const int bid = blockIdx.x;
  const int f = bid >> 5;        // fold 0..7
  const int zh = bid & 31;       // all fold-blocks of a zh share an XCD (%8)
  const int z = zh >> 2;
  const int h = zh & 3;
  const int start = seq_offsets[z];
  const size_t tbase = (size_t)(zh * 32) * TILE_B;
  const int spanA = 2 * f + 2;   // iters for phase A (m-tile f); total = 34

  int mt = f;
  int wm0 = mt * 128 + w * 32;
  int mrow = wm0 + l31;

  h8 qf[8];
  fx16 oacc[4];

  auto loadQ = [&]() {
    const float* qrow = qkv + (size_t)(start + mrow) * QKV_STRIDE + h * (3 * DH);
#pragma unroll
    for (int ks = 0; ks < 8; ++ks) {
      const int d0 = ks * 16 + lh * 8;
      float4 a = *(const float4*)(qrow + d0);
      float4 b = *(const float4*)(qrow + d0 + 4);
      a.x *= QSCALE; a.y *= QSCALE; a.z *= QSCALE; a.w *= QSCALE;
      b.x *= QSCALE; b.y *= QSCALE; b.z *= QSCALE; b.w *= QSCALE;
      qf[ks] = cvt8(a, b);
    }
  };
  auto zeroAcc = [&]() {
#pragma unroll
    for (int db = 0; db < 4; ++db)
#pragma unroll
      for (int i = 0; i < 16; ++i) oacc[db][i] = 0.0f;
  };
  auto flushAcc = [&]() {
#pragma unroll
    for (int db = 0; db < 4; ++db) {
      const int d = db * 32 + l31;
#pragma unroll
      for (int i = 0; i < 16; ++i) {
        const int m = wm0 + (i & 3) + 8 * (i >> 2) + 4 * lh;
        out[(size_t)(start + m) * OUT_STRIDE + h * DH + d] = oacc[db][i];
      }
    }
  };
  // stage kv-tile kt2 into buffer buf (8 global_load_lds per wave)
  auto stage = [&](int buf, int kt2) {
    const char* kg = k16 + tbase + (size_t)kt2 * TILE_B + w * 4096 + lane * 16;
    const char* vg = vt + tbase + (size_t)kt2 * TILE_B + w * 4096 + lane * 16;
    u16t* kl = &Ks[buf][w * 2048];
    u16t* vl = &Vs[buf][w * 2048];
#pragma unroll
    for (int i = 0; i < 4; ++i) {
      GLDS(kg + i * 1024, kl + i * 512);
      GLDS(vg + i * 1024, vl + i * 512);
    }
  };

  loadQ();
  zeroAcc();
  int buf = 0;
  stage(0, 0);
  __syncthreads();  // tile 0 landed

  for (int j = 0; j < 34; ++j) {
    if (j == spanA) {  // phase switch: flush tile-f output, move to tile 15-f
      flushAcc();
      mt = 15 - f;
      wm0 = mt * 128 + w * 32;
      mrow = wm0 + l31;
      loadQ();
      zeroAcc();
    }
    const int kt = (j < spanA) ? j : j - spanA;
    if (j + 1 < 34) stage(buf ^ 1, (j + 1 == spanA) ? 0 : kt + 1);

    const int n0 = kt * 64;
    if (n0 <= wm0 + 31) {
      const char* kb = (const char*)&Ks[buf][0];
      const char* vb = (const char*)&Vs[buf][0];

      // ---- batch ALL 16 K-fragment reads (independent -> pipelined) ----
      h8 a0[8], a1[8];
      const int sw = (l31 & 7) << 4;
#pragma unroll
      for (int ks = 0; ks < 8; ++ks) {
        const int cb = 32 * ks + 16 * lh;
        a0[ks] = *(const h8*)(kb + l31 * 256 + (cb ^ sw));
        a1[ks] = *(const h8*)(kb + (32 + l31) * 256 + (cb ^ sw));
      }
      // ---- S^T = K Q^T ----
      fx16 s0, s1;
#pragma unroll
      for (int i = 0; i < 16; ++i) { s0[i] = 0.0f; s1[i] = 0.0f; }
      __builtin_amdgcn_s_setprio(1);
#pragma unroll
      for (int ks = 0; ks < 8; ++ks) {
        s0 = __builtin_amdgcn_mfma_f32_32x32x16_f16(a0[ks], qf[ks], s0, 0, 0, 0);
        s1 = __builtin_amdgcn_mfma_f32_32x32x16_f16(a1[ks], qf[ks], s1, 0, 0, 0);
      }
      __builtin_amdgcn_s_setprio(0);

      // ---- batch ALL 16 V-fragment reads; silu VALU hides their latency ----
      h8 bv[4][4];
#pragma unroll
      for (int ks = 0; ks < 4; ++ks) {
        const int cb = 32 * ks + 16 * lh;
#pragma unroll
        for (int db = 0; db < 4; ++db) {
          const int rr = db * 32 + l31;
          bv[ks][db] = *(const h8*)(vb + rr * 128 + (cb ^ ((rr & 7) << 4)));
        }
      }
      // ---- silu + mask (in-register), pack to PV A-fragments ----
      const bool needmask = (n0 + 63 > wm0);
      silu_mask(s0, 0, needmask, n0, mrow, lh);
      silu_mask(s1, 32, needmask, n0, mrow, lh);
      h8 pa[4];
      pa[0] = pack8(s0, 0);
      pa[1] = pack8(s0, 8);
      pa[2] = pack8(s1, 0);
      pa[3] = pack8(s1, 8);
      // ---- O += P V ----
      __builtin_amdgcn_s_setprio(1);
#pragma unroll
      for (int ks = 0; ks < 4; ++ks) {
#pragma unroll
        for (int db = 0; db < 4; ++db) {
          oacc[db] = __builtin_amdgcn_mfma_f32_32x32x16_f16(pa[ks], bv[ks][db], oacc[db], 0, 0, 0);
        }
      }
      __builtin_amdgcn_s_setprio(0);
    }
    __syncthreads();  // drain next-tile loads + gate buffer reuse
    buf ^= 1;
  }
  flushAcc();  // phase B epilogue
}

// ---------------------------------------------------------------------------
// Never-expected fallback (ws too small): naive per-(token,head) block.
// ---------------------------------------------------------------------------
__global__ __launch_bounds__(128) void fallback_kernel(const float* __restrict__ qkv,
                                                       const int* __restrict__ seq_offsets,
                                                       float* __restrict__ out) {
  const int token = blockIdx.x;
  const int h = blockIdx.y;
  const int z = token >> 11;
  const int m = token & 2047;
  const int start = seq_offsets[z];
  const int t = threadIdx.x;  // = d
  const float qd = qkv[(size_t)(start + m) * QKV_STRIDE + h * (3 * DH) + t] * ALPHA;
  __shared__ float red[2];
  float acc = 0.0f;
  for (int n = 0; n <= m; ++n) {
    const float kd = qkv[(size_t)(start + n) * QKV_STRIDE + h * (3 * DH) + DH + t];
    float part = qd * kd;
#pragma unroll
    for (int o = 32; o; o >>= 1) part += __shfl_down(part, o);
    if ((t & 63) == 0) red[t >> 6] = part;
    __syncthreads();
    const float s = red[0] + red[1];
    const float sil = s / ((1.0f + __expf(-s)) * 2048.0f);
    acc += sil * qkv[(size_t)(start + n) * QKV_STRIDE + h * (3 * DH) + 2 * DH + t];
    __syncthreads();
  }
  out[(size_t)(start + m) * OUT_STRIDE + h * DH + t] = acc;
}

// ---------------------------------------------------------------------------
extern "C" void kernel_launch(void* const* d_in, const int* in_sizes, int n_in,
                              void* d_out, int out_size, void* d_ws, size_t ws_size,
                              hipStream_t stream) {
  (void)in_sizes; (void)n_in; (void)out_size;
  const float* qkv = (const float*)d_in[0];
  const int* seq_offsets = (const int*)d_in[1];
  // d_in[2..4] (timestamps, ts_weights, pos_weights) unused by the reference.
  float* out = (float*)d_out;

  const size_t half = (size_t)ZSEQ * NH * 32 * TILE_B;  // 16 MiB (bytes)

  if (ws_size >= 2 * half) {
    char* k16 = (char*)d_ws;
    char* vt = k16 + half;
    prep_kernel<<<ZSEQ * NH * (NSEQ / 64), 256, 0, stream>>>(qkv, seq_offsets, k16, vt);
    // 20KB dynamic LDS reserve (unused) forces 1 block/CU (84KB > 160/2 KB).
    attn_kernel<<<ZSEQ * NH * 8, 256, 20480, stream>>>(qkv, seq_offsets, k16, vt, out);
  } else {
    fallback_kernel<<<dim3(ZSEQ * NSEQ, NH), 128, 0, stream>>>(qkv, seq_offsets, out);
  }
}

// Round 9
// 92.654 us; speedup vs baseline: 3.3659x; 1.0495x over previous
//
#include <hip/hip_runtime.h>
#include <cstdint>
#include <cstddef>

// Problem constants (fixed by setup_inputs)
#define ZSEQ 8
#define NSEQ 2048
#define NH 4
#define DH 128
#define QKV_STRIDE (NH * 3 * DH) /* 1536 floats per token row */
#define OUT_STRIDE (NH * DH)     /* 512 floats per token row */
#define ALPHA 0.08838834764831843f
#define LOG2E 1.4426950408889634f
#define QSCALE (ALPHA * LOG2E)                 /* fold log2e into Q */
#define VSCALE (1.0f / (2048.0f * LOG2E))      /* fold 1/(2048*log2e) into V */
#define TILE_B 16384             /* bytes per 64-row K tile / per V tile */

typedef _Float16 h8 __attribute__((ext_vector_type(8)));
typedef __fp16 fp16x2 __attribute__((ext_vector_type(2)));
typedef float fx16 __attribute__((ext_vector_type(16)));
typedef unsigned int ui4v __attribute__((ext_vector_type(4)));
typedef unsigned short u16t;

// global_load_lds: per-lane global src, wave-uniform LDS base (HW adds lane*16)
#define GLDS(gp, lp)                                                        \
  __builtin_amdgcn_global_load_lds(                                         \
      (__attribute__((address_space(1))) void*)(gp),                        \
      (__attribute__((address_space(3))) void*)(lp), 16, 0, 0)

__device__ __forceinline__ h8 cvt8(float4 a, float4 b) {
  h8 r;
  r[0] = (_Float16)a.x; r[1] = (_Float16)a.y; r[2] = (_Float16)a.z; r[3] = (_Float16)a.w;
  r[4] = (_Float16)b.x; r[5] = (_Float16)b.y; r[6] = (_Float16)b.z; r[7] = (_Float16)b.w;
  return r;
}

__device__ __forceinline__ unsigned pku(float a, float b) {
  union { fp16x2 h; unsigned u; } c;
  c.h = __builtin_amdgcn_cvt_pkrtz(a, b);
  return c.u;
}

// ---------------------------------------------------------------------------
// Prep: qkv f32 -> pre-swizzled f16 tiles in d_ws.
//   K tiles: [zh][nt][64 rows x 256B], byte col c stored at c ^ ((row&7)<<4)
//   V tiles: [zh][nt][128 d-rows x 128B], col c stored at c ^ ((d&7)<<4)
//   V values pre-scaled by VSCALE (silu exp2/2048 folding).
//   V tile COLUMN ORDER is bit2<->bit3 swapped in n (pi(c) = swap bits 2,3):
//   column c holds V row n0 + pi(c). This matches the natural per-lane order
//   of S^T fragments after swapped-QK^T MFMA, so PV needs NO cross-lane ops.
// ---------------------------------------------------------------------------
__global__ __launch_bounds__(256) void prep_kernel(const float* __restrict__ qkv,
                                                   const int* __restrict__ seq_offsets,
                                                   char* __restrict__ k16,
                                                   char* __restrict__ vt) {
  __shared__ u16t Vl[64 * 136];  // padded transpose staging
  const int t = threadIdx.x;
  const int b = blockIdx.x;
  const int z = b >> 7;
  const int h = (b >> 5) & 3;
  const int nb = b & 31;
  const int n0 = nb * 64;
  const int start = seq_offsets[z];
  const int zh = z * NH + h;
  const size_t tb = (size_t)(zh * 32 + nb) * TILE_B;

#pragma unroll
  for (int i = 0; i < 2; ++i) {
    const int r = i * 32 + (t >> 3);
    const int c16 = (t & 7) * 16;  // element col
    const int cb = c16 * 2;        // byte col
    const float* src = qkv + (size_t)(start + n0 + r) * QKV_STRIDE + h * (3 * DH);
    // ---- K (swizzled) ----
    float4 a0 = *(const float4*)(src + DH + c16);
    float4 a1 = *(const float4*)(src + DH + c16 + 4);
    float4 a2 = *(const float4*)(src + DH + c16 + 8);
    float4 a3 = *(const float4*)(src + DH + c16 + 12);
    char* kd = k16 + tb + r * 256;
    *(h8*)(kd + (cb ^ ((r & 7) << 4))) = cvt8(a0, a1);
    *(h8*)(kd + ((cb + 16) ^ ((r & 7) << 4))) = cvt8(a2, a3);
    // ---- V -> LDS (row-major, padded), pre-scaled by VSCALE ----
    float4 v0 = *(const float4*)(src + 2 * DH + c16);
    float4 v1 = *(const float4*)(src + 2 * DH + c16 + 4);
    float4 v2 = *(const float4*)(src + 2 * DH + c16 + 8);
    float4 v3 = *(const float4*)(src + 2 * DH + c16 + 12);
    v0.x *= VSCALE; v0.y *= VSCALE; v0.z *= VSCALE; v0.w *= VSCALE;
    v1.x *= VSCALE; v1.y *= VSCALE; v1.z *= VSCALE; v1.w *= VSCALE;
    v2.x *= VSCALE; v2.y *= VSCALE; v2.z *= VSCALE; v2.w *= VSCALE;
    v3.x *= VSCALE; v3.y *= VSCALE; v3.z *= VSCALE; v3.w *= VSCALE;
    *(h8*)((char*)Vl + r * 272 + cb) = cvt8(v0, v1);
    *(h8*)((char*)Vl + r * 272 + cb + 16) = cvt8(v2, v3);
  }
  __syncthreads();
  // transpose out: V tile rows = d, cols = n with pi (bits 2,3 of n swapped)
#pragma unroll
  for (int j = 0; j < 2; ++j) {
    const int d = j * 64 + (t >> 2);
    const int n16 = (t & 3) * 16;
    const int cn = n16 * 2;  // byte col of this 16-col group
    h8 o0, o1;
#pragma unroll
    for (int k2 = 0; k2 < 8; ++k2) {
      const int r0 = (k2 & 3) + 8 * (k2 >> 2);
      o0[k2] = *(const _Float16*)((const char*)Vl + (n16 + r0) * 272 + d * 2);
      o1[k2] = *(const _Float16*)((const char*)Vl + (n16 + 4 + r0) * 272 + d * 2);
    }
    char* vd = vt + tb + d * 128;
    *(h8*)(vd + (cn ^ ((d & 7) << 4))) = o0;
    *(h8*)(vd + ((cn + 16) ^ ((d & 7) << 4))) = o1;
  }
}

// silu + causal mask on one S^T accumulator (in place).
// s holds s2 = (alpha*log2e) * q.k; silu_ref/2048 = VSCALE * s2*rcp(1+2^-s2),
// with VSCALE folded into V. s element i at n = n0+nbase+(i&3)+8*(i>>2)+4*lh.
__device__ __forceinline__ void silu_mask(fx16& s, int nbase, bool needmask, int n0,
                                          int mrow, int lh) {
#pragma unroll
  for (int i = 0; i < 16; ++i) {
    const float sv = s[i];
    const float e2 = __builtin_amdgcn_exp2f(-sv);
    float sil = sv * __builtin_amdgcn_rcpf(1.0f + e2);
    if (needmask && (n0 + nbase + (i & 3) + 8 * (i >> 2) + 4 * lh > mrow)) sil = 0.0f;
    s[i] = sil;
  }
}

// pack 8 consecutive s elements (b = 0 or 8) into an f16 A-fragment.
__device__ __forceinline__ h8 pack8(const fx16& s, int b) {
  union { ui4v u; h8 h; } cv;
  cv.u = (ui4v){pku(s[b + 0], s[b + 1]), pku(s[b + 2], s[b + 3]),
                pku(s[b + 4], s[b + 5]), pku(s[b + 6], s[b + 7])};
  return cv.h;
}

// ---------------------------------------------------------------------------
// Attention r9 "sequential fold, 2-wave blocks": 512 blocks = 32 zh x 16
// folds, 128 threads (2 waves), BM=64 (32 rows/wave), KV tile 64, double-
// buffered 64KB LDS -> EXACTLY 2 blocks/CU co-resident = 2 waves/SIMD, so one
// wave's VALU (silu) overlaps the other's MFMA/LDS (separate pipes, m114).
// Block fold s computes m-subtile s (span s+1 kv-tiles) THEN subtile 31-s
// (span 32-s): 33 staged tiles for EVERY block -> uniform durations, no tail.
// Inner loop identical to verified r4/r6/r8 (swapped QK^T, in-reg silu,
// pi-permuted V, batched LDS reads, setprio).
// ---------------------------------------------------------------------------
__global__ __launch_bounds__(128, 2) void attn_kernel(const float* __restrict__ qkv,
                                                      const int* __restrict__ seq_offsets,
                                                      const char* __restrict__ k16,
                                                      const char* __restrict__ vt,
                                                      float* __restrict__ out) {
  __shared__ u16t Ks[2][64 * 128];   // 16KB per buf
  __shared__ u16t Vs[2][128 * 64];   // 16KB per buf

  const int t = threadIdx.x;
  const int lane = t & 63;
  const int w = t >> 6;          // 0/1
  const int l31 = lane & 31;
  const int lh = lane >> 5;

  const int bid = blockIdx.x;
  const int s = bid >> 5;        // fold 0..15
  const int zh = bid & 31;       // 4 distinct zh per XCD (bid%8 round-robin)
  const int z = zh >> 2;
  const int h = zh & 3;
  const int start = seq_offsets[z];
  const size_t tbase = (size_t)(zh * 32) * TILE_B;
  const int spanA = s + 1;       // iters for phase A (m-subtile s); total = 33

  int mt = s;                    // 64-row m-subtile index (0..31)
  int wm0 = mt * 64 + w * 32;
  int mrow = wm0 + l31;

  h8 qf[8];
  fx16 oacc[4];

  auto loadQ = [&]() {
    const float* qrow = qkv + (size_t)(start + mrow) * QKV_STRIDE + h * (3 * DH);
#pragma unroll
    for (int ks = 0; ks < 8; ++ks) {
      const int d0 = ks * 16 + lh * 8;
      float4 a = *(const float4*)(qrow + d0);
      float4 b = *(const float4*)(qrow + d0 + 4);
      a.x *= QSCALE; a.y *= QSCALE; a.z *= QSCALE; a.w *= QSCALE;
      b.x *= QSCALE; b.y *= QSCALE; b.z *= QSCALE; b.w *= QSCALE;
      qf[ks] = cvt8(a, b);
    }
  };
  auto zeroAcc = [&]() {
#pragma unroll
    for (int db = 0; db < 4; ++db)
#pragma unroll
      for (int i = 0; i < 16; ++i) oacc[db][i] = 0.0f;
  };
  auto flushAcc = [&]() {
#pragma unroll
    for (int db = 0; db < 4; ++db) {
      const int d = db * 32 + l31;
#pragma unroll
      for (int i = 0; i < 16; ++i) {
        const int m = wm0 + (i & 3) + 8 * (i >> 2) + 4 * lh;
        out[(size_t)(start + m) * OUT_STRIDE + h * DH + d] = oacc[db][i];
      }
    }
  };
  // stage kv-tile kt2 into buffer buf (16 global_load_lds per wave)
  auto stage = [&](int buf, int kt2) {
    const char* kg = k16 + tbase + (size_t)kt2 * TILE_B + w * 8192 + lane * 16;
    const char* vg = vt + tbase + (size_t)kt2 * TILE_B + w * 8192 + lane * 16;
    u16t* kl = &Ks[buf][w * 4096];  // u16 units: 4096 u16 = 8KB per wave
    u16t* vl = &Vs[buf][w * 4096];
#pragma unroll
    for (int i = 0; i < 8; ++i) {
      GLDS(kg + i * 1024, kl + i * 512);
      GLDS(vg + i * 1024, vl + i * 512);
    }
  };

  loadQ();
  zeroAcc();
  int buf = 0;
  stage(0, 0);
  __syncthreads();  // tile 0 landed

  for (int j = 0; j < 33; ++j) {
    if (j == spanA) {  // phase switch: flush subtile-s output, move to 31-s
      flushAcc();
      mt = 31 - s;
      wm0 = mt * 64 + w * 32;
      mrow = wm0 + l31;
      loadQ();
      zeroAcc();
    }
    const int kt = (j < spanA) ? j : j - spanA;
    if (j + 1 < 33) stage(buf ^ 1, (j + 1 == spanA) ? 0 : kt + 1);

    const int n0 = kt * 64;
    {
      const char* kb = (const char*)&Ks[buf][0];
      const char* vb = (const char*)&Vs[buf][0];

      // ---- batch ALL 16 K-fragment reads (independent -> pipelined) ----
      h8 a0[8], a1[8];
      const int sw = (l31 & 7) << 4;
#pragma unroll
      for (int ks = 0; ks < 8; ++ks) {
        const int cb = 32 * ks + 16 * lh;
        a0[ks] = *(const h8*)(kb + l31 * 256 + (cb ^ sw));
        a1[ks] = *(const h8*)(kb + (32 + l31) * 256 + (cb ^ sw));
      }
      // ---- S^T = K Q^T ----
      fx16 s0, s1;
#pragma unroll
      for (int i = 0; i < 16; ++i) { s0[i] = 0.0f; s1[i] = 0.0f; }
      __builtin_amdgcn_s_setprio(1);
#pragma unroll
      for (int ks = 0; ks < 8; ++ks) {
        s0 = __builtin_amdgcn_mfma_f32_32x32x16_f16(a0[ks], qf[ks], s0, 0, 0, 0);
        s1 = __builtin_amdgcn_mfma_f32_32x32x16_f16(a1[ks], qf[ks], s1, 0, 0, 0);
      }
      __builtin_amdgcn_s_setprio(0);

      // ---- batch ALL 16 V-fragment reads; silu VALU hides their latency ----
      h8 bv[4][4];
#pragma unroll
      for (int ks = 0; ks < 4; ++ks) {
        const int cb = 32 * ks + 16 * lh;
#pragma unroll
        for (int db = 0; db < 4; ++db) {
          const int rr = db * 32 + l31;
          bv[ks][db] = *(const h8*)(vb + rr * 128 + (cb ^ ((rr & 7) << 4)));
        }
      }
      // ---- silu + mask (in-register), pack to PV A-fragments ----
      const bool needmask = (n0 + 63 > wm0);
      silu_mask(s0, 0, needmask, n0, mrow, lh);
      silu_mask(s1, 32, needmask, n0, mrow, lh);
      h8 pa[4];
      pa[0] = pack8(s0, 0);
      pa[1] = pack8(s0, 8);
      pa[2] = pack8(s1, 0);
      pa[3] = pack8(s1, 8);
      // ---- O += P V ----
      __builtin_amdgcn_s_setprio(1);
#pragma unroll
      for (int ks = 0; ks < 4; ++ks) {
#pragma unroll
        for (int db = 0; db < 4; ++db) {
          oacc[db] = __builtin_amdgcn_mfma_f32_32x32x16_f16(pa[ks], bv[ks][db], oacc[db], 0, 0, 0);
        }
      }
      __builtin_amdgcn_s_setprio(0);
    }
    __syncthreads();  // drain next-tile loads + gate buffer reuse
    buf ^= 1;
  }
  flushAcc();  // phase B epilogue
}

// ---------------------------------------------------------------------------
// Never-expected fallback (ws too small): naive per-(token,head) block.
// ---------------------------------------------------------------------------
__global__ __launch_bounds__(128) void fallback_kernel(const float* __restrict__ qkv,
                                                       const int* __restrict__ seq_offsets,
                                                       float* __restrict__ out) {
  const int token = blockIdx.x;
  const int h = blockIdx.y;
  const int z = token >> 11;
  const int m = token & 2047;
  const int start = seq_offsets[z];
  const int t = threadIdx.x;  // = d
  const float qd = qkv[(size_t)(start + m) * QKV_STRIDE + h * (3 * DH) + t] * ALPHA;
  __shared__ float red[2];
  float acc = 0.0f;
  for (int n = 0; n <= m; ++n) {
    const float kd = qkv[(size_t)(start + n) * QKV_STRIDE + h * (3 * DH) + DH + t];
    float part = qd * kd;
#pragma unroll
    for (int o = 32; o; o >>= 1) part += __shfl_down(part, o);
    if ((t & 63) == 0) red[t >> 6] = part;
    __syncthreads();
    const float s = red[0] + red[1];
    const float sil = s / ((1.0f + __expf(-s)) * 2048.0f);
    acc += sil * qkv[(size_t)(start + n) * QKV_STRIDE + h * (3 * DH) + 2 * DH + t];
    __syncthreads();
  }
  out[(size_t)(start + m) * OUT_STRIDE + h * DH + t] = acc;
}

// ---------------------------------------------------------------------------
extern "C" void kernel_launch(void* const* d_in, const int* in_sizes, int n_in,
                              void* d_out, int out_size, void* d_ws, size_t ws_size,
                              hipStream_t stream) {
  (void)in_sizes; (void)n_in; (void)out_size;
  const float* qkv = (const float*)d_in[0];
  const int* seq_offsets = (const int*)d_in[1];
  // d_in[2..4] (timestamps, ts_weights, pos_weights) unused by the reference.
  float* out = (float*)d_out;

  const size_t half = (size_t)ZSEQ * NH * 32 * TILE_B;  // 16 MiB (bytes)

  if (ws_size >= 2 * half) {
    char* k16 = (char*)d_ws;
    char* vt = k16 + half;
    prep_kernel<<<ZSEQ * NH * (NSEQ / 64), 256, 0, stream>>>(qkv, seq_offsets, k16, vt);
    attn_kernel<<<ZSEQ * NH * 16, 128, 0, stream>>>(qkv, seq_offsets, k16, vt, out);
  } else {
    fallback_kernel<<<dim3(ZSEQ * NSEQ, NH), 128, 0, stream>>>(qkv, seq_offsets, out);
  }
}